// Round 5
// baseline (184.958 us; speedup 1.0000x reference)
//
#include <hip/hip_runtime.h>
#include <hip/hip_bf16.h>

// SNN spike layer: causal alpha-PSP conv (K<=77) + sequential refractory scan.
//
// R5: block-level producer/consumer. 64 neurons/block, 256 thr (4 waves),
// 1024 blocks = 4 blocks/CU = 16 waves/CU (R1-R4 had 1 wave/SIMD: VALUBusy
// stuck at 54% with nothing to hide latency). Conv is parallel over (n,t):
// wave q computes t in [q*8, q*8+8) per 32-t chunk; u handed via LDS to
// wave 0 which runs the sequential scan (pend in wave-0 regs); waves slide
// the spike-history window via race-free mod-32 chains. LDS time-major
// [col][n], stride 65: every access <=2 lanes/bank (free), all ds offsets
// compile-time immediates. Conv j-order kept bit-identical to R1-R4
// (absmax was 0.0).

#define T_LEN 300
#define NB 64            // neurons per block
#define NTH 256
#define TC 32            // timesteps per full chunk
#define NFULL 9          // 9*32 = 288
#define TAIL 12          // 288 + 12 = 300
#define KS 77
#define KR 10
#define THETA_V 10.0f
#define STR 65           // LDS col stride in floats: bank = (65c+n)%32 = (c+n)%32
#define U_COLS 32
#define SP_OFF (U_COLS * STR)              // u region: 2080 floats
#define SP_COLS 108                        // 76 history + 32 current
#define LDS_FLOATS (SP_OFF + SP_COLS * STR)  // 9100 floats = 36,400 B -> 4 blocks/CU

__global__ __launch_bounds__(NTH, 4) void spike_layer_kernel(
    const float* __restrict__ spike_in,
    const float* __restrict__ srm, int srm_len,
    const float* __restrict__ refk, int ref_len,
    float* __restrict__ out)
{
    __shared__ float lds[LDS_FLOATS];

    const int tid = threadIdx.x;
    const int n   = tid & 63;        // neuron within block
    const int q   = tid >> 6;        // wave index 0..3
    const int row = blockIdx.x * NB + n;

    const float* inR  = spike_in + (size_t)row * T_LEN;
    float*       outR = out      + (size_t)row * T_LEN;

    // uniform loads -> SGPRs where possible
    float srm_r[KS];
#pragma unroll
    for (int i = 0; i < KS; ++i) srm_r[i] = (i < srm_len) ? srm[i] : 0.0f;

    float rt[KR], pend[KR];
#pragma unroll
    for (int i = 0; i < KR; ++i) {
        rt[i]   = (i + 1 < ref_len) ? refk[i + 1] : 0.0f;
        pend[i] = 0.0f;
    }

    float* uB   = &lds[n];                  // u[c][n]  at uB[c*STR]
    float* spB  = &lds[SP_OFF + n];         // sp[col][n] at spB[col*STR]
    float* spQ8 = spB + (q * 8) * STR;      // conv col base for this wave
    float* uQ8  = uB  + (q * 8) * STR;
    float* chB  = spB + q * STR;            // slide-chain base: col (4k+q) = chB + k*4*STR

    // ---- init: zero history cols [0..75]; load t[0..31] -> cols [76..107]
    float4 g0 = *(const float4*)(inR + q * 8);
    float4 g1 = *(const float4*)(inR + q * 8 + 4);
#pragma unroll
    for (int k = 0; k < 8; ++k) {           // chain cols c=4k+q: c, c+32, (c<12: c+64)
        chB[(4 * k) * STR]      = 0.0f;
        chB[(4 * k + 32) * STR] = 0.0f;
        if (k < 3) chB[(4 * k + 64) * STR] = 0.0f;
    }
    {
        float* d = spB + (76 + q * 8) * STR;
        d[0] = g0.x; d[STR] = g0.y; d[2*STR] = g0.z; d[3*STR] = g0.w;
        d[4*STR] = g1.x; d[5*STR] = g1.y; d[6*STR] = g1.z; d[7*STR] = g1.w;
    }
    __syncthreads();

#pragma unroll 1
    for (int ch = 0; ch < NFULL; ++ch) {
        // prefetch next chunk (in flight through the whole conv)
        if (ch < NFULL - 1) {
            const float* p = inR + (ch + 1) * TC + q * 8;
            g0 = *(const float4*)p;
            g1 = *(const float4*)(p + 4);
        } else {                              // tail: only 12 floats, no OOB
            if (q == 0)      { g0 = *(const float4*)(inR + 288); g1 = *(const float4*)(inR + 292); }
            else if (q == 1) { g0 = *(const float4*)(inR + 296); }
        }

        // conv: u[k] for t = ch*32 + q*8 + k; window rel-cols R in [0..83] desc
        // (per-accumulator tap order j ascending == R1-R4 bit order)
        float u[8];
#pragma unroll
        for (int k = 0; k < 8; ++k) u[k] = 0.0f;
#pragma unroll
        for (int R = 83; R >= 0; --R) {
            float h = spQ8[R * STR];
#pragma unroll
            for (int k = 0; k < 8; ++k) {
                const int j = k + 76 - R;
                if (j >= 0 && j <= 76) u[k] = fmaf(srm_r[j], h, u[k]);
            }
        }
#pragma unroll
        for (int k = 0; k < 8; ++k) uQ8[k * STR] = u[k];

        __syncthreads();   // A: u complete; conv's sp reads done

        // wave 0: sequential scan of 32 steps (writes s back into u region)
        if (q == 0) {
#pragma unroll
            for (int c = 0; c < U_COLS; ++c) {
                float ue = uB[c * STR] + pend[0];
                float s  = (ue >= THETA_V) ? 1.0f : 0.0f;
#pragma unroll
                for (int i = 0; i < KR - 1; ++i) pend[i] = fmaf(s, rt[i], pend[i + 1]);
                pend[KR - 1] = s * rt[KR - 1];
                uB[c * STR] = s;
            }
        }

        // all waves: slide window left by 32 via disjoint mod-32 chains
        // chain c = 4k+q: dst c <- c+32; c+32 <- c+64; (c<12: c+64 <- c+96)
#pragma unroll
        for (int k = 0; k < 8; ++k) {
            float* cp = chB + (4 * k) * STR;
            float a = cp[32 * STR];
            float b = cp[64 * STR];
            if (k < 3) {
                float c2 = cp[96 * STR];
                cp[0] = a; cp[32 * STR] = b; cp[64 * STR] = c2;
            } else {
                cp[0] = a; cp[32 * STR] = b;
            }
        }

        __syncthreads();   // B: scan + slide done

        // install prefetched chunk into cols [76..107]
        if (ch < NFULL - 1) {
            float* d = spB + (76 + q * 8) * STR;
            d[0] = g0.x; d[STR] = g0.y; d[2*STR] = g0.z; d[3*STR] = g0.w;
            d[4*STR] = g1.x; d[5*STR] = g1.y; d[6*STR] = g1.z; d[7*STR] = g1.w;
        } else {
            if (q == 0) {
                float* d = spB + 76 * STR;
                d[0] = g0.x; d[STR] = g0.y; d[2*STR] = g0.z; d[3*STR] = g0.w;
                d[4*STR] = g1.x; d[5*STR] = g1.y; d[6*STR] = g1.z; d[7*STR] = g1.w;
            } else if (q == 1) {
                float* d = spB + 84 * STR;
                d[0] = g0.x; d[STR] = g0.y; d[2*STR] = g0.z; d[3*STR] = g0.w;
            }
        }

        // store this chunk's spikes
        {
            float* o = outR + ch * TC + q * 8;
            float4 s0, s1;
            s0.x = uQ8[0];       s0.y = uQ8[STR];     s0.z = uQ8[2*STR]; s0.w = uQ8[3*STR];
            s1.x = uQ8[4*STR];   s1.y = uQ8[5*STR];   s1.z = uQ8[6*STR]; s1.w = uQ8[7*STR];
            *(float4*)o = s0;
            *(float4*)(o + 4) = s1;
        }

        __syncthreads();   // C: sp install visible; u region free for next conv
    }

    // ---- tail: t in [288..299], window cols [0..87]
    {
        float* spQ3 = spB + (q * 3) * STR;
        float u[3] = {0.0f, 0.0f, 0.0f};
#pragma unroll
        for (int R = 78; R >= 0; --R) {
            float h = spQ3[R * STR];
#pragma unroll
            for (int k = 0; k < 3; ++k) {
                const int j = k + 76 - R;
                if (j >= 0 && j <= 76) u[k] = fmaf(srm_r[j], h, u[k]);
            }
        }
        float* uQ3 = uB + (q * 3) * STR;
#pragma unroll
        for (int k = 0; k < 3; ++k) uQ3[k * STR] = u[k];
    }
    __syncthreads();
    if (q == 0) {
#pragma unroll
        for (int c = 0; c < TAIL; ++c) {
            float ue = uB[c * STR] + pend[0];
            float s  = (ue >= THETA_V) ? 1.0f : 0.0f;
#pragma unroll
            for (int i = 0; i < KR - 1; ++i) pend[i] = fmaf(s, rt[i], pend[i + 1]);
            pend[KR - 1] = s * rt[KR - 1];
            uB[c * STR] = s;
        }
    }
    __syncthreads();
    {
        float* uQ3 = uB + (q * 3) * STR;
        float* o   = outR + 288 + q * 3;
        o[0] = uQ3[0]; o[1] = uQ3[STR]; o[2] = uQ3[2 * STR];
    }
}

extern "C" void kernel_launch(void* const* d_in, const int* in_sizes, int n_in,
                              void* d_out, int out_size, void* d_ws, size_t ws_size,
                              hipStream_t stream) {
    const float* spike_in = (const float*)d_in[0];
    const float* srm      = (const float*)d_in[1];
    const float* refk     = (const float*)d_in[2];
    float* out = (float*)d_out;

    int srm_len = in_sizes[1];
    int ref_len = in_sizes[2];
    int B = in_sizes[0] / T_LEN;        // 65536 neurons (divisible by 64)

    int grid = B / NB;                  // 1024 blocks -> 4 per CU
    spike_layer_kernel<<<grid, NTH, 0, stream>>>(spike_in, srm, srm_len,
                                                 refk, ref_len, out);
}